// Round 13
// baseline (339.021 us; speedup 1.0000x reference)
//
#include <hip/hip_runtime.h>
#include <hip/hip_bf16.h>

// Problem constants (fixed by reference):
//   B=4, T=2048, C=1024, H=16, Dh=64, qkv N = 3072, M = B*T = 8192.
#define T_SEQ 2048
#define D_EMB 1024
#define NH    16
#define DH    64
#define NB    4
#define MROWS (NB * T_SEQ)      // 8192
#define QKVN  (3 * D_EMB)       // 3072

typedef __attribute__((ext_vector_type(8))) short bf16x8;   // 8 bf16 = 4 VGPR
typedef __attribute__((ext_vector_type(4))) float f32x4;

__device__ __forceinline__ unsigned short f2bf(float f) {
  __hip_bfloat16 h = __float2bfloat16(f);
  return __builtin_bit_cast(unsigned short, h);
}

__device__ __forceinline__ void gload_lds16(const void* g, void* lds) {
  __builtin_amdgcn_global_load_lds(
      (const __attribute__((address_space(1))) void*)g,
      (__attribute__((address_space(3))) void*)lds, 16, 0, 0);
}

// ---------------------------------------------------------------- cvt f32->bf16
__global__ __launch_bounds__(256) void cvt_kernel(const float* __restrict__ in,
                                                  unsigned short* __restrict__ out,
                                                  int n4) {
  for (int i = blockIdx.x * 256 + threadIdx.x; i < n4; i += gridDim.x * 256) {
    const float4 v = reinterpret_cast<const float4*>(in)[i];
    ushort4 o;
    o.x = f2bf(v.x); o.y = f2bf(v.y); o.z = f2bf(v.z); o.w = f2bf(v.w);
    reinterpret_cast<ushort4*>(out)[i] = o;
  }
}

// ---------------------------------------------------------------- V transpose
// vt[bh][d][t] from qkv's V third. Padded LDS tile kills bank conflicts.
__global__ __launch_bounds__(256) void transposeV(const unsigned short* __restrict__ qkv,
                                                  unsigned short* __restrict__ vt) {
  __shared__ __align__(16) unsigned short Lt[64 * 72];
  const int tid = threadIdx.x;
  const int t0 = blockIdx.x * 64;
  const int bh = blockIdx.y;
  const int b  = bh >> 4;
  const int h  = bh & 15;
  const unsigned short* src = qkv + (size_t)(b * T_SEQ) * QKVN + 2 * D_EMB + h * DH;
#pragma unroll
  for (int g = 0; g < 2; ++g) {
    const int r = (tid >> 3) + g * 32;
    const int c = tid & 7;
    bf16x8 v = *reinterpret_cast<const bf16x8*>(src + (size_t)(t0 + r) * QKVN + c * 8);
    *reinterpret_cast<bf16x8*>(reinterpret_cast<char*>(Lt) + r * 144 + c * 16) = v;
  }
  __syncthreads();
#pragma unroll
  for (int g = 0; g < 2; ++g) {
    const int d  = (tid >> 3) + g * 32;
    const int tc = tid & 7;
    bf16x8 o;
#pragma unroll
    for (int j = 0; j < 8; ++j)
      ((unsigned short*)&o)[j] = Lt[(tc * 8 + j) * 72 + d];
    *reinterpret_cast<bf16x8*>(vt + ((size_t)bh * 64 + d) * T_SEQ + t0 + tc * 8) = o;
  }
}

// ---------------------------------------------------------------- GEMM  C = A * Bt^T + bias
// (unchanged this round — 128x128, BK=64, XOR-swizzled, XCD block swizzle)
template <int OUT_BF16>
__global__ __launch_bounds__(256) void gemm_bt(const unsigned short* __restrict__ A,
                                               const unsigned short* __restrict__ Bt,
                                               const float* __restrict__ bias,
                                               void* __restrict__ Cout,
                                               int M, int N, int K) {
  __shared__ __align__(16) unsigned short As[128 * 64];
  __shared__ __align__(16) unsigned short Bs[128 * 64];

  const int tid = threadIdx.x;
  const int w  = tid >> 6;
  const int l  = tid & 63;
  const int lr = l & 15;
  const int lg = l >> 4;

  const int gx   = gridDim.x;
  const int nwg  = gx * gridDim.y;
  const int orig = blockIdx.y * gx + blockIdx.x;
  const int swz  = (orig & 7) * (nwg >> 3) + (orig >> 3);
  const int bm = (swz / gx) * 128;
  const int bn = (swz % gx) * 128;

  const int wr = (w >> 1) * 64;
  const int wc = (w & 1) * 64;

  f32x4 acc[4][4];
#pragma unroll
  for (int i = 0; i < 4; ++i)
#pragma unroll
    for (int j = 0; j < 4; ++j) acc[i][j] = (f32x4){0.f, 0.f, 0.f, 0.f};

  const int cj = (l & 7) ^ (l >> 3);
  const unsigned short* Ab = A + (size_t)(bm + w * 32 + (l >> 3)) * K + cj * 8;
  const unsigned short* Bb = Bt + (size_t)(bn + w * 32 + (l >> 3)) * K + cj * 8;

  for (int kt = 0; kt < K; kt += 64) {
#pragma unroll
    for (int i = 0; i < 4; ++i) {
      gload_lds16(Ab + kt + (size_t)(i * 8) * K, &As[(w * 32 + i * 8) * 64]);
      gload_lds16(Bb + kt + (size_t)(i * 8) * K, &Bs[(w * 32 + i * 8) * 64]);
    }
    __syncthreads();

#pragma unroll
    for (int kk = 0; kk < 2; ++kk) {
      bf16x8 a[4], b[4];
#pragma unroll
      for (int mi = 0; mi < 4; ++mi) {
        const int R = wr + mi * 16 + lr;
        a[mi] = *reinterpret_cast<const bf16x8*>(
            &As[R * 64 + (((kk * 4 + lg) ^ (lr & 7)) << 3)]);
      }
#pragma unroll
      for (int ni = 0; ni < 4; ++ni) {
        const int R = wc + ni * 16 + lr;
        b[ni] = *reinterpret_cast<const bf16x8*>(
            &Bs[R * 64 + (((kk * 4 + lg) ^ (lr & 7)) << 3)]);
      }
#pragma unroll
      for (int mi = 0; mi < 4; ++mi)
#pragma unroll
        for (int ni = 0; ni < 4; ++ni)
          acc[mi][ni] = __builtin_amdgcn_mfma_f32_16x16x32_bf16(a[mi], b[ni], acc[mi][ni], 0, 0, 0);
    }
    __syncthreads();
  }

#pragma unroll
  for (int mi = 0; mi < 4; ++mi)
#pragma unroll
    for (int ni = 0; ni < 4; ++ni)
#pragma unroll
      for (int i = 0; i < 4; ++i) {
        const int row = bm + wr + mi * 16 + lg * 4 + i;
        const int col = bn + wc + ni * 16 + lr;
        const float v = acc[mi][ni][i] + bias[col];
        if (OUT_BF16)
          ((unsigned short*)Cout)[(size_t)row * N + col] = f2bf(v);
        else
          ((float*)Cout)[(size_t)row * N + col] = v;
      }
}

// ---------------------------------------------------------------- flash attention (causal)
// Block: 512 thr (8 waves). MERGED paired q-tiles: one KV sweep serves BOTH
// q-tiles (A=bx, B=15-bx); each tile staged ONCE (nt=32-2bx vs 34 before),
// kf fragments shared by both groups' QK^T. T13 defer-max (THR=8, exp2 dom).
// XOR-swizzled LDS; K and V(pre-transposed) staged via gload_lds.
__global__ __launch_bounds__(512, 4) void attn_fwd(const unsigned short* __restrict__ qkv,
                                                   const unsigned short* __restrict__ vt,
                                                   unsigned short* __restrict__ attn_out,
                                                   const int* __restrict__ causal_flag) {
  __shared__ __align__(16) unsigned short Ks[64 * 64];
  __shared__ __align__(16) unsigned short Vs[64 * 64];     // V^T[d][k] (swizzled)
  __shared__ __align__(16) unsigned short Ps[8][16 * 64];  // per-wave P (swizzled)

  const int tid = threadIdx.x;
  const int w  = tid >> 6;          // wave 0..7
  const int l  = tid & 63;
  const int lr = l & 15;
  const int lg = l >> 4;
  const int lk = lg * 8;
  const int bx = blockIdx.x;        // 0..7
  const int bh = blockIdx.y;        // 0..63
  const int b  = bh >> 4;
  const int h  = bh & 15;
  const int causal = causal_flag[0];

  const unsigned short* Qp  = qkv + (size_t)(b * T_SEQ) * QKVN + h * DH;
  const unsigned short* Kp  = Qp + D_EMB;
  const unsigned short* Vtp = vt + (size_t)bh * 64 * T_SEQ;

  const int scj = (l & 7) ^ (l >> 3);    // pre-swizzled chunk for staging
  const int srr = l >> 3;                // row-in-8 this lane stages

  const int qtA = bx, qtB = 15 - bx;
  const int wrowA = qtA * 128 + w * 16;
  const int wrowB = qtB * 128 + w * 16;

  // Q fragments for both groups, pre-scaled by 0.125*log2(e)
  bf16x8 qfA[2], qfB[2];
#pragma unroll
  for (int ks = 0; ks < 2; ++ks) {
#pragma unroll
    for (int g = 0; g < 2; ++g) {
      const int wr0 = g ? wrowB : wrowA;
      bf16x8 v = *reinterpret_cast<const bf16x8*>(
          Qp + (size_t)(wr0 + lr) * QKVN + ks * 32 + lk);
#pragma unroll
      for (int j = 0; j < 8; ++j) {
        const float f = __builtin_bit_cast(float, ((unsigned)(unsigned short)v[j]) << 16)
                        * 0.180336879f;   // 0.125 * log2(e)
        v[j] = (short)(__builtin_bit_cast(unsigned, f) >> 16);
      }
      if (g) qfB[ks] = v; else qfA[ks] = v;
    }
  }

  f32x4 oaccA[4], oaccB[4];
  float mA = -INFINITY, lA = 0.f, mB = -INFINITY, lB = 0.f;
#pragma unroll
  for (int di = 0; di < 4; ++di) {
    oaccA[di] = (f32x4){0.f, 0.f, 0.f, 0.f};
    oaccB[di] = (f32x4){0.f, 0.f, 0.f, 0.f};
  }

  const int nt = causal ? (2 * qtB + 2) : (T_SEQ / 64);

  // softmax + P-write + PV for one group (defer-max, THR=8 in exp2 domain)
  auto softmax_pv = [&](f32x4 (&s)[4], float& mrow, float& lsum, f32x4 (&oacc)[4],
                        const int wrow0, const int kbase) {
    const bool mm = causal && (kbase + 63 > wrow0);
    if (mm) {
      const int qrow_rel = wrow0 + lr - kbase;
#pragma unroll
      for (int ni = 0; ni < 4; ++ni)
#pragma unroll
        for (int i = 0; i < 4; ++i)
          if (ni * 16 + lg * 4 + i > qrow_rel) s[ni][i] = -INFINITY;
    }
    float pmax = -INFINITY;
#pragma unroll
    for (int ni = 0; ni < 4; ++ni)
#pragma unroll
      for (int i = 0; i < 4; ++i) pmax = fmaxf(pmax, s[ni][i]);
    pmax = fmaxf(pmax, __shfl_xor(pmax, 16));
    pmax = fmaxf(pmax, __shfl_xor(pmax, 32));
    if (!__all(pmax <= mrow + 8.f)) {          // T13: rescale only on real growth
      const float mnew = fmaxf(mrow, pmax);
      const float alpha = exp2f(mrow - mnew);
      lsum *= alpha;
      mrow = mnew;
#pragma unroll
      for (int i = 0; i < 4; ++i) {
        const float a_bc = __shfl(alpha, (l & 48) | (lg * 4 + i));
#pragma unroll
        for (int di = 0; di < 4; ++di) oacc[di][i] *= a_bc;
      }
    }
    float psum = 0.f;
#pragma unroll
    for (int ni = 0; ni < 4; ++ni)
#pragma unroll
      for (int i = 0; i < 4; ++i) {
        const float p = exp2f(s[ni][i] - mrow);   // bounded by 2^8
        s[ni][i] = p;
        psum += p;
      }
    psum += __shfl_xor(psum, 16);
    psum += __shfl_xor(psum, 32);
    lsum += psum;
    // P -> LDS (packed b64, swizzled)
#pragma unroll
    for (int ni = 0; ni < 4; ++ni) {
      const unsigned lo = (unsigned)f2bf(s[ni][0]) | ((unsigned)f2bf(s[ni][1]) << 16);
      const unsigned hi = (unsigned)f2bf(s[ni][2]) | ((unsigned)f2bf(s[ni][3]) << 16);
      const int chunk = (ni * 2 + (lg >> 1)) ^ (lr & 7);
      uint2* dst = reinterpret_cast<uint2*>(
          reinterpret_cast<char*>(&Ps[w][0]) + lr * 128 + chunk * 16 + (lg & 1) * 8);
      *dst = make_uint2(lo, hi);
    }
    // O += P V
#pragma unroll
    for (int ks2 = 0; ks2 < 2; ++ks2) {
      bf16x8 pf, vf[4];
      pf = *reinterpret_cast<const bf16x8*>(
          &Ps[w][lr * 64 + (((ks2 * 4 + lg) ^ (lr & 7)) << 3)]);
#pragma unroll
      for (int di = 0; di < 4; ++di) {
        const int R = di * 16 + lr;
        vf[di] = *reinterpret_cast<const bf16x8*>(
            &Vs[R * 64 + (((ks2 * 4 + lg) ^ (lr & 7)) << 3)]);
      }
#pragma unroll
      for (int di = 0; di < 4; ++di)
        oacc[di] = __builtin_amdgcn_mfma_f32_16x16x32_bf16(pf, vf[di], oacc[di], 0, 0, 0);
    }
  };

  for (int kb = 0; kb < nt; ++kb) {
    const int kbase = kb * 64;
    // ---- stage K and V^T (once per tile, serves both groups)
    gload_lds16(Kp + (size_t)(kbase + w * 8 + srr) * QKVN + scj * 8,
                &Ks[(w * 8) * 64]);
    gload_lds16(Vtp + (size_t)(w * 8 + srr) * T_SEQ + kbase + scj * 8,
                &Vs[(w * 8) * 64]);
    __syncthreads();

    const bool liveA = !causal || (kbase <= wrowA + 15);

    // ---- QK^T for both groups, kf shared
    f32x4 sA[4], sB[4];
#pragma unroll
    for (int ni = 0; ni < 4; ++ni) {
      sB[ni] = (f32x4){0.f, 0.f, 0.f, 0.f};
      sA[ni] = (f32x4){0.f, 0.f, 0.f, 0.f};
    }
#pragma unroll
    for (int ks = 0; ks < 2; ++ks) {
      bf16x8 kf[4];
#pragma unroll
      for (int ni = 0; ni < 4; ++ni) {
        const int R = ni * 16 + lr;
        kf[ni] = *reinterpret_cast<const bf16x8*>(
            &Ks[R * 64 + (((ks * 4 + lg) ^ (lr & 7)) << 3)]);
      }
#pragma unroll
      for (int ni = 0; ni < 4; ++ni)
        sB[ni] = __builtin_amdgcn_mfma_f32_16x16x32_bf16(kf[ni], qfB[ks], sB[ni], 0, 0, 0);
      if (liveA) {
#pragma unroll
        for (int ni = 0; ni < 4; ++ni)
          sA[ni] = __builtin_amdgcn_mfma_f32_16x16x32_bf16(kf[ni], qfA[ks], sA[ni], 0, 0, 0);
      }
    }

    softmax_pv(sB, mB, lB, oaccB, wrowB, kbase);
    if (liveA) softmax_pv(sA, mA, lA, oaccA, wrowA, kbase);

    __syncthreads();
  }

  // ---- epilogue: normalize + store both groups
#pragma unroll
  for (int g = 0; g < 2; ++g) {
    const int wr0 = g ? wrowB : wrowA;
    const float lsum = g ? lB : lA;
#pragma unroll
    for (int i = 0; i < 4; ++i) {
      const float ls = __shfl(lsum, (l & 48) | (lg * 4 + i));
      const float inv = 1.0f / ls;
#pragma unroll
      for (int di = 0; di < 4; ++di) {
        const int q = wr0 + lg * 4 + i;
        const int d = di * 16 + lr;
        const f32x4& oa = g ? oaccB[di] : oaccA[di];
        attn_out[(size_t)(b * T_SEQ + q) * D_EMB + h * DH + d] = f2bf(oa[i] * inv);
      }
    }
  }
}

// ---------------------------------------------------------------- launch
extern "C" void kernel_launch(void* const* d_in, const int* in_sizes, int n_in,
                              void* d_out, int out_size, void* d_ws, size_t ws_size,
                              hipStream_t stream) {
  const float* x     = (const float*)d_in[0];
  const float* W_in  = (const float*)d_in[1];
  const float* b_in  = (const float*)d_in[2];
  const float* W_out = (const float*)d_in[3];
  const float* b_out = (const float*)d_in[4];
  const int*   causal = (const int*)d_in[5];
  float* out = (float*)d_out;

  char* ws = (char*)d_ws;
  unsigned short* x_bf    = (unsigned short*)(ws);            // dead after in_proj
  unsigned short* vt      = (unsigned short*)(ws);            // reuses x_bf region
  unsigned short* win_bf  = (unsigned short*)(ws + 16777216);
  unsigned short* wout_bf = (unsigned short*)(ws + 23068672);
  unsigned short* qkv     = (unsigned short*)(ws + 25165824);
  unsigned short* attn    = (unsigned short*)(ws + 75497472);

  cvt_kernel<<<2048, 256, 0, stream>>>(x, x_bf, (MROWS * D_EMB) / 4);
  cvt_kernel<<<2048, 256, 0, stream>>>(W_in, win_bf, (QKVN * D_EMB) / 4);
  cvt_kernel<<<1024, 256, 0, stream>>>(W_out, wout_bf, (D_EMB * D_EMB) / 4);

  gemm_bt<1><<<dim3(QKVN / 128, MROWS / 128), 256, 0, stream>>>(
      x_bf, win_bf, b_in, qkv, MROWS, QKVN, D_EMB);

  transposeV<<<dim3(T_SEQ / 64, NB * NH), 256, 0, stream>>>(qkv, vt);

  attn_fwd<<<dim3(8, NB * NH), 512, 0, stream>>>(qkv, vt, attn, causal);

  gemm_bt<0><<<dim3(D_EMB / 128, MROWS / 128), 256, 0, stream>>>(
      attn, wout_bf, b_out, out, MROWS, D_EMB, D_EMB);
}

// Round 15
// 290.269 us; speedup vs baseline: 1.1680x; 1.1680x over previous
//
#include <hip/hip_runtime.h>
#include <hip/hip_bf16.h>

// Problem constants (fixed by reference):
//   B=4, T=2048, C=1024, H=16, Dh=64, qkv N = 3072, M = B*T = 8192.
#define T_SEQ 2048
#define D_EMB 1024
#define NH    16
#define DH    64
#define NB    4
#define MROWS (NB * T_SEQ)      // 8192
#define QKVN  (3 * D_EMB)       // 3072

typedef __attribute__((ext_vector_type(8))) short bf16x8;   // 8 bf16 = 4 VGPR
typedef __attribute__((ext_vector_type(4))) float f32x4;

__device__ __forceinline__ unsigned short f2bf(float f) {
  __hip_bfloat16 h = __float2bfloat16(f);
  return __builtin_bit_cast(unsigned short, h);
}

__device__ __forceinline__ void gload_lds16(const void* g, void* lds) {
  __builtin_amdgcn_global_load_lds(
      (const __attribute__((address_space(1))) void*)g,
      (__attribute__((address_space(3))) void*)lds, 16, 0, 0);
}

// ---------------------------------------------------------------- cvt f32->bf16
__global__ __launch_bounds__(256) void cvt_kernel(const float* __restrict__ in,
                                                  unsigned short* __restrict__ out,
                                                  int n4) {
  for (int i = blockIdx.x * 256 + threadIdx.x; i < n4; i += gridDim.x * 256) {
    const float4 v = reinterpret_cast<const float4*>(in)[i];
    ushort4 o;
    o.x = f2bf(v.x); o.y = f2bf(v.y); o.z = f2bf(v.z); o.w = f2bf(v.w);
    reinterpret_cast<ushort4*>(out)[i] = o;
  }
}

// ---------------------------------------------------------------- V transpose
// vt[bh][d][t] from qkv's V third. Padded LDS tile kills bank conflicts.
__global__ __launch_bounds__(256) void transposeV(const unsigned short* __restrict__ qkv,
                                                  unsigned short* __restrict__ vt) {
  __shared__ __align__(16) unsigned short Lt[64 * 72];
  const int tid = threadIdx.x;
  const int t0 = blockIdx.x * 64;
  const int bh = blockIdx.y;
  const int b  = bh >> 4;
  const int h  = bh & 15;
  const unsigned short* src = qkv + (size_t)(b * T_SEQ) * QKVN + 2 * D_EMB + h * DH;
#pragma unroll
  for (int g = 0; g < 2; ++g) {
    const int r = (tid >> 3) + g * 32;
    const int c = tid & 7;
    bf16x8 v = *reinterpret_cast<const bf16x8*>(src + (size_t)(t0 + r) * QKVN + c * 8);
    *reinterpret_cast<bf16x8*>(reinterpret_cast<char*>(Lt) + r * 144 + c * 16) = v;
  }
  __syncthreads();
#pragma unroll
  for (int g = 0; g < 2; ++g) {
    const int d  = (tid >> 3) + g * 32;
    const int tc = tid & 7;
    bf16x8 o;
#pragma unroll
    for (int j = 0; j < 8; ++j)
      ((unsigned short*)&o)[j] = Lt[(tc * 8 + j) * 72 + d];
    *reinterpret_cast<bf16x8*>(vt + ((size_t)bh * 64 + d) * T_SEQ + t0 + tc * 8) = o;
  }
}

// ---------------------------------------------------------------- GEMM  C = A * Bt^T + bias
// (unchanged — 128x128, BK=64, XOR-swizzled, XCD block swizzle; part of the
//  measured 296us baseline)
template <int OUT_BF16>
__global__ __launch_bounds__(256) void gemm_bt(const unsigned short* __restrict__ A,
                                               const unsigned short* __restrict__ Bt,
                                               const float* __restrict__ bias,
                                               void* __restrict__ Cout,
                                               int M, int N, int K) {
  __shared__ __align__(16) unsigned short As[128 * 64];
  __shared__ __align__(16) unsigned short Bs[128 * 64];

  const int tid = threadIdx.x;
  const int w  = tid >> 6;
  const int l  = tid & 63;
  const int lr = l & 15;
  const int lg = l >> 4;

  const int gx   = gridDim.x;
  const int nwg  = gx * gridDim.y;
  const int orig = blockIdx.y * gx + blockIdx.x;
  const int swz  = (orig & 7) * (nwg >> 3) + (orig >> 3);
  const int bm = (swz / gx) * 128;
  const int bn = (swz % gx) * 128;

  const int wr = (w >> 1) * 64;
  const int wc = (w & 1) * 64;

  f32x4 acc[4][4];
#pragma unroll
  for (int i = 0; i < 4; ++i)
#pragma unroll
    for (int j = 0; j < 4; ++j) acc[i][j] = (f32x4){0.f, 0.f, 0.f, 0.f};

  const int cj = (l & 7) ^ (l >> 3);
  const unsigned short* Ab = A + (size_t)(bm + w * 32 + (l >> 3)) * K + cj * 8;
  const unsigned short* Bb = Bt + (size_t)(bn + w * 32 + (l >> 3)) * K + cj * 8;

  for (int kt = 0; kt < K; kt += 64) {
#pragma unroll
    for (int i = 0; i < 4; ++i) {
      gload_lds16(Ab + kt + (size_t)(i * 8) * K, &As[(w * 32 + i * 8) * 64]);
      gload_lds16(Bb + kt + (size_t)(i * 8) * K, &Bs[(w * 32 + i * 8) * 64]);
    }
    __syncthreads();

#pragma unroll
    for (int kk = 0; kk < 2; ++kk) {
      bf16x8 a[4], b[4];
#pragma unroll
      for (int mi = 0; mi < 4; ++mi) {
        const int R = wr + mi * 16 + lr;
        a[mi] = *reinterpret_cast<const bf16x8*>(
            &As[R * 64 + (((kk * 4 + lg) ^ (lr & 7)) << 3)]);
      }
#pragma unroll
      for (int ni = 0; ni < 4; ++ni) {
        const int R = wc + ni * 16 + lr;
        b[ni] = *reinterpret_cast<const bf16x8*>(
            &Bs[R * 64 + (((kk * 4 + lg) ^ (lr & 7)) << 3)]);
      }
#pragma unroll
      for (int mi = 0; mi < 4; ++mi)
#pragma unroll
        for (int ni = 0; ni < 4; ++ni)
          acc[mi][ni] = __builtin_amdgcn_mfma_f32_16x16x32_bf16(a[mi], b[ni], acc[mi][ni], 0, 0, 0);
    }
    __syncthreads();
  }

#pragma unroll
  for (int mi = 0; mi < 4; ++mi)
#pragma unroll
    for (int ni = 0; ni < 4; ++ni)
#pragma unroll
      for (int i = 0; i < 4; ++i) {
        const int row = bm + wr + mi * 16 + lg * 4 + i;
        const int col = bn + wc + ni * 16 + lr;
        const float v = acc[mi][ni][i] + bias[col];
        if (OUT_BF16)
          ((unsigned short*)Cout)[(size_t)row * N + col] = f2bf(v);
        else
          ((float*)Cout)[(size_t)row * N + col] = v;
      }
}

// ---------------------------------------------------------------- flash attention (causal)
// REVERTED to r11 structure (sequential paired q-tiles; merge regressed via
// scratch spill + block imbalance, r13). Added in isolation:
//  - T13 defer-max (THR=8, exp2 domain): skip O-rescale unless real max growth
//  - explicit mm branch: mask VALU only on diagonal-intersecting tiles
__global__ __launch_bounds__(512, 4) void attn_fwd(const unsigned short* __restrict__ qkv,
                                                   const unsigned short* __restrict__ vt,
                                                   unsigned short* __restrict__ attn_out,
                                                   const int* __restrict__ causal_flag) {
  __shared__ __align__(16) unsigned short Ks[64 * 64];
  __shared__ __align__(16) unsigned short Vs[64 * 64];     // V^T[d][k] (swizzled)
  __shared__ __align__(16) unsigned short Ps[8][16 * 64];  // per-wave P (swizzled)

  const int tid = threadIdx.x;
  const int w  = tid >> 6;          // wave 0..7
  const int l  = tid & 63;
  const int lr = l & 15;
  const int lg = l >> 4;
  const int lk = lg * 8;
  const int bx = blockIdx.x;        // 0..7
  const int bh = blockIdx.y;        // 0..63
  const int b  = bh >> 4;
  const int h  = bh & 15;
  const int causal = causal_flag[0];

  const unsigned short* Qp  = qkv + (size_t)(b * T_SEQ) * QKVN + h * DH;
  const unsigned short* Kp  = Qp + D_EMB;
  const unsigned short* Vtp = vt + (size_t)bh * 64 * T_SEQ;

  const int scj = (l & 7) ^ (l >> 3);    // pre-swizzled chunk for staging
  const int srr = l >> 3;                // row-in-8 this lane stages
  const int bclane = (l & 48) | 0;       // broadcast base (lg*4+i added per i)

  for (int qq = 0; qq < 2; ++qq) {
    const int qt = qq ? (15 - bx) : bx;
    const int qbase = qt * 128;
    const int wrow0 = qbase + w * 16;          // this wave's first q-row

    // Q fragments, pre-scaled by 0.125*log2(e) (exp2-domain softmax)
    bf16x8 qf[2];
#pragma unroll
    for (int ks = 0; ks < 2; ++ks) {
      bf16x8 v = *reinterpret_cast<const bf16x8*>(
          Qp + (size_t)(wrow0 + lr) * QKVN + ks * 32 + lk);
#pragma unroll
      for (int j = 0; j < 8; ++j) {
        const float f = __builtin_bit_cast(float, ((unsigned)(unsigned short)v[j]) << 16)
                        * 0.180336879f;   // 0.125 * log2(e)
        v[j] = (short)(__builtin_bit_cast(unsigned, f) >> 16);
      }
      qf[ks] = v;
    }

    f32x4 oacc[4];
    float mrow = -INFINITY, lsum = 0.f;    // stats for q-row (wrow0+lr)
#pragma unroll
    for (int di = 0; di < 4; ++di) oacc[di] = (f32x4){0.f, 0.f, 0.f, 0.f};

    const int nt = causal ? (qt * 2 + 2) : (T_SEQ / 64);

    for (int kb = 0; kb < nt; ++kb) {
      const int kbase = kb * 64;
      // ---- stage K rows [w*8,w*8+8) and V^T rows [w*8,w*8+8), swizzled src
      gload_lds16(Kp + (size_t)(kbase + w * 8 + srr) * QKVN + scj * 8,
                  &Ks[(w * 8) * 64]);
      gload_lds16(Vtp + (size_t)(w * 8 + srr) * T_SEQ + kbase + scj * 8,
                  &Vs[(w * 8) * 64]);
      __syncthreads();

      // waves whose 16 rows are entirely above this KV tile skip compute
      const bool live = !causal || (kbase <= wrow0 + 15);
      if (live) {
        // ---- S^T = K Q^T: s[ni][i] = S[k=kbase+ni*16+lg*4+i][q=wrow0+lr]
        f32x4 s[4];
#pragma unroll
        for (int ni = 0; ni < 4; ++ni) s[ni] = (f32x4){0.f, 0.f, 0.f, 0.f};
#pragma unroll
        for (int ks = 0; ks < 2; ++ks) {
          bf16x8 kf[4];
#pragma unroll
          for (int ni = 0; ni < 4; ++ni) {
            const int R = ni * 16 + lr;
            kf[ni] = *reinterpret_cast<const bf16x8*>(
                &Ks[R * 64 + (((ks * 4 + lg) ^ (lr & 7)) << 3)]);
          }
#pragma unroll
          for (int ni = 0; ni < 4; ++ni)
            s[ni] = __builtin_amdgcn_mfma_f32_16x16x32_bf16(kf[ni], qf[ks], s[ni], 0, 0, 0);
        }

        // ---- online softmax (exp2 domain), row-local in lane
        float pmax = -INFINITY;
        const bool mm = causal && (kbase + 63 > wrow0);
        if (mm) {   // diagonal tile: apply causal mask (rare branch)
          const int qrow_rel = wrow0 + lr - kbase;
#pragma unroll
          for (int ni = 0; ni < 4; ++ni)
#pragma unroll
            for (int i = 0; i < 4; ++i) {
              float v = s[ni][i];
              if (ni * 16 + lg * 4 + i > qrow_rel) v = -INFINITY;
              s[ni][i] = v;
              pmax = fmaxf(pmax, v);
            }
        } else {
#pragma unroll
          for (int ni = 0; ni < 4; ++ni)
#pragma unroll
            for (int i = 0; i < 4; ++i) pmax = fmaxf(pmax, s[ni][i]);
        }
        pmax = fmaxf(pmax, __shfl_xor(pmax, 16));
        pmax = fmaxf(pmax, __shfl_xor(pmax, 32));

        // T13 defer-max: rescale only when the running max truly grows
        if (!__all(pmax <= mrow + 8.f)) {
          const float mnew = fmaxf(mrow, pmax);
          const float alpha = exp2f(mrow - mnew);
          lsum *= alpha;
          mrow = mnew;
#pragma unroll
          for (int i = 0; i < 4; ++i) {
            const float a_bc = __shfl(alpha, bclane | (lg * 4 + i));
#pragma unroll
            for (int di = 0; di < 4; ++di) oacc[di][i] *= a_bc;
          }
        }

        float psum = 0.f;
#pragma unroll
        for (int ni = 0; ni < 4; ++ni)
#pragma unroll
          for (int i = 0; i < 4; ++i) {
            const float p = exp2f(s[ni][i] - mrow);   // bounded by 2^8
            s[ni][i] = p;
            psum += p;
          }
        psum += __shfl_xor(psum, 16);
        psum += __shfl_xor(psum, 32);
        lsum += psum;

        // ---- P -> LDS: 4x ds_write_b64 (packed bf16), swizzled layout
#pragma unroll
        for (int ni = 0; ni < 4; ++ni) {
          const unsigned lo = (unsigned)f2bf(s[ni][0]) | ((unsigned)f2bf(s[ni][1]) << 16);
          const unsigned hi = (unsigned)f2bf(s[ni][2]) | ((unsigned)f2bf(s[ni][3]) << 16);
          const int chunk = (ni * 2 + (lg >> 1)) ^ (lr & 7);
          uint2* dst = reinterpret_cast<uint2*>(
              reinterpret_cast<char*>(&Ps[w][0]) + lr * 128 + chunk * 16 + (lg & 1) * 8);
          *dst = make_uint2(lo, hi);
        }

        // ---- O += P V (swizzled reads; Ps is per-wave, no barrier needed)
#pragma unroll
        for (int ks2 = 0; ks2 < 2; ++ks2) {
          bf16x8 pf, vf[4];
          pf = *reinterpret_cast<const bf16x8*>(
              &Ps[w][lr * 64 + (((ks2 * 4 + lg) ^ (lr & 7)) << 3)]);
#pragma unroll
          for (int di = 0; di < 4; ++di) {
            const int R = di * 16 + lr;
            vf[di] = *reinterpret_cast<const bf16x8*>(
                &Vs[R * 64 + (((ks2 * 4 + lg) ^ (lr & 7)) << 3)]);
          }
#pragma unroll
          for (int di = 0; di < 4; ++di)
            oacc[di] = __builtin_amdgcn_mfma_f32_16x16x32_bf16(pf, vf[di], oacc[di], 0, 0, 0);
        }
      }
      __syncthreads();
    }

    // ---- epilogue: normalize + store bf16 (lsum broadcast to oacc row layout)
#pragma unroll
    for (int i = 0; i < 4; ++i) {
      const float ls = __shfl(lsum, bclane | (lg * 4 + i));
      const float inv = 1.0f / ls;
#pragma unroll
      for (int di = 0; di < 4; ++di) {
        const int q = wrow0 + lg * 4 + i;
        const int d = di * 16 + lr;
        attn_out[(size_t)(b * T_SEQ + q) * D_EMB + h * DH + d] =
            f2bf(oacc[di][i] * inv);
      }
    }
  }
}

// ---------------------------------------------------------------- launch
extern "C" void kernel_launch(void* const* d_in, const int* in_sizes, int n_in,
                              void* d_out, int out_size, void* d_ws, size_t ws_size,
                              hipStream_t stream) {
  const float* x     = (const float*)d_in[0];
  const float* W_in  = (const float*)d_in[1];
  const float* b_in  = (const float*)d_in[2];
  const float* W_out = (const float*)d_in[3];
  const float* b_out = (const float*)d_in[4];
  const int*   causal = (const int*)d_in[5];
  float* out = (float*)d_out;

  char* ws = (char*)d_ws;
  unsigned short* x_bf    = (unsigned short*)(ws);            // dead after in_proj
  unsigned short* vt      = (unsigned short*)(ws);            // reuses x_bf region
  unsigned short* win_bf  = (unsigned short*)(ws + 16777216);
  unsigned short* wout_bf = (unsigned short*)(ws + 23068672);
  unsigned short* qkv     = (unsigned short*)(ws + 25165824);
  unsigned short* attn    = (unsigned short*)(ws + 75497472);

  cvt_kernel<<<2048, 256, 0, stream>>>(x, x_bf, (MROWS * D_EMB) / 4);
  cvt_kernel<<<2048, 256, 0, stream>>>(W_in, win_bf, (QKVN * D_EMB) / 4);
  cvt_kernel<<<1024, 256, 0, stream>>>(W_out, wout_bf, (D_EMB * D_EMB) / 4);

  gemm_bt<1><<<dim3(QKVN / 128, MROWS / 128), 256, 0, stream>>>(
      x_bf, win_bf, b_in, qkv, MROWS, QKVN, D_EMB);

  transposeV<<<dim3(T_SEQ / 64, NB * NH), 256, 0, stream>>>(qkv, vt);

  attn_fwd<<<dim3(8, NB * NH), 512, 0, stream>>>(qkv, vt, attn, causal);

  gemm_bt<0><<<dim3(D_EMB / 128, MROWS / 128), 256, 0, stream>>>(
      attn, wout_bf, b_out, out, MROWS, D_EMB, D_EMB);
}